// Round 1
// baseline (45.924 us; speedup 1.0000x reference)
//
#include <hip/hip_runtime.h>
#include <math.h>

// DISTANA fused prediction-kernel step.
// Shapes: B=128, N=4096, IN=9, PRE=4, CELLS=16, OUT=9.
// Outputs concatenated: y (B,N,9) | new_h (B,N,16) | new_cell (B,N,16), all f32.

#define NB 128
#define NN 4096
#define NNODES (NB * NN)   // 524288
#define IN_DIM 9
#define PRE_DIM 4
#define CELLS 16
#define OUT_DIM 9

__device__ __forceinline__ float fast_tanh(float x) {
    // tanh(x) = (e^{2x}-1)/(e^{2x}+1), clamped so e never overflows.
    x = fminf(fmaxf(x, -15.f), 15.f);
    float e = __expf(2.f * x);
    return (e - 1.f) / (e + 1.f);
}

__global__ __launch_bounds__(256) void distana_step_kernel(
    const float* __restrict__ input,      // (B,N,9,1) -> (B,N,9)
    const float* __restrict__ w_pre,      // (9,4)
    const float* __restrict__ w_lstm,     // (4,16)
    const float* __restrict__ w_post,     // (16,9)
    const float* __restrict__ old_h,      // (B,N,16)
    const float* __restrict__ old_cell,   // (B,N,16)
    float* __restrict__ y,                // (B,N,9)
    float* __restrict__ new_h,            // (B,N,16)
    float* __restrict__ new_cell)         // (B,N,16)
{
    __shared__ float sWpre[IN_DIM * PRE_DIM];    // 36
    __shared__ float sWl[PRE_DIM * CELLS];       // 64
    __shared__ float sWp[CELLS * OUT_DIM];       // 144

    const int t = threadIdx.x;
    if (t < IN_DIM * PRE_DIM)  sWpre[t] = w_pre[t];
    if (t < PRE_DIM * CELLS)   sWl[t]   = w_lstm[t];
    if (t < CELLS * OUT_DIM)   sWp[t]   = w_post[t];
    __syncthreads();

    const int idx = blockIdx.x * 256 + t;        // node index, grid sized exactly

    // ---- load input x (9 floats, contiguous per node) ----
    const float* xin = input + (size_t)idx * IN_DIM;
    float x[IN_DIM];
#pragma unroll
    for (int i = 0; i < IN_DIM; ++i) x[i] = xin[i];

    // ---- pre = tanh(x @ W_pre)  (9->4) ----
    float pre[PRE_DIM];
#pragma unroll
    for (int p = 0; p < PRE_DIM; ++p) {
        float s = 0.f;
#pragma unroll
        for (int i = 0; i < IN_DIM; ++i)
            s = fmaf(x[i], sWpre[i * PRE_DIM + p], s);
        pre[p] = fast_tanh(s);
    }

    // ---- load old_h / old_cell as float4 (64B-aligned per node) ----
    const float4* hp = (const float4*)(old_h   + (size_t)idx * CELLS);
    const float4* cp = (const float4*)(old_cell + (size_t)idx * CELLS);
    float oh[CELLS], oc[CELLS];
#pragma unroll
    for (int q = 0; q < 4; ++q) {
        float4 h4 = hp[q];
        float4 c4 = cp[q];
        oh[q*4+0]=h4.x; oh[q*4+1]=h4.y; oh[q*4+2]=h4.z; oh[q*4+3]=h4.w;
        oc[q*4+0]=c4.x; oc[q*4+1]=c4.y; oc[q*4+2]=c4.z; oc[q*4+3]=c4.w;
    }

    // ---- net = pre @ W_lstm + old_h; CIFG gate; new_cell; new_h ----
    float nh[CELLS], nc[CELLS];
#pragma unroll
    for (int c = 0; c < CELLS; ++c) {
        float s = oh[c];
#pragma unroll
        for (int p = 0; p < PRE_DIM; ++p)
            s = fmaf(pre[p], sWl[p * CELLS + c], s);
        // share one exp for sigmoid(i) and tanh(g)
        s = fminf(fmaxf(s, -15.f), 15.f);
        float e  = __expf(s);
        float ig = e / (1.f + e);            // sigmoid(net)
        float e2 = e * e;                    // e^{2*net}
        float g  = (e2 - 1.f) / (e2 + 1.f);  // tanh(net)
        float ncv = (1.f - ig) * oc[c] + ig * g;
        nc[c] = ncv;
        nh[c] = fast_tanh(ncv);
    }

    // ---- y = tanh(new_h @ W_post)  (16->9) ----
    float* yout = y + (size_t)idx * OUT_DIM;
#pragma unroll
    for (int o = 0; o < OUT_DIM; ++o) {
        float s = 0.f;
#pragma unroll
        for (int c = 0; c < CELLS; ++c)
            s = fmaf(nh[c], sWp[c * OUT_DIM + o], s);
        yout[o] = fast_tanh(s);
    }

    // ---- store new_h / new_cell as float4 ----
    float4* nhp = (float4*)(new_h   + (size_t)idx * CELLS);
    float4* ncp = (float4*)(new_cell + (size_t)idx * CELLS);
#pragma unroll
    for (int q = 0; q < 4; ++q) {
        nhp[q] = make_float4(nh[q*4+0], nh[q*4+1], nh[q*4+2], nh[q*4+3]);
        ncp[q] = make_float4(nc[q*4+0], nc[q*4+1], nc[q*4+2], nc[q*4+3]);
    }
}

extern "C" void kernel_launch(void* const* d_in, const int* in_sizes, int n_in,
                              void* d_out, int out_size, void* d_ws, size_t ws_size,
                              hipStream_t stream) {
    const float* input    = (const float*)d_in[0];  // (B,N,9,1)
    const float* w_pre    = (const float*)d_in[1];  // (9,4)
    const float* w_lstm   = (const float*)d_in[2];  // (4,16)
    const float* w_post   = (const float*)d_in[3];  // (16,9)
    const float* old_h    = (const float*)d_in[4];  // (B,N,16)
    const float* old_cell = (const float*)d_in[5];  // (B,N,16)

    float* out = (float*)d_out;
    float* y        = out;                                    // B*N*9
    float* new_h    = out + (size_t)NNODES * OUT_DIM;         // B*N*16
    float* new_cell = new_h + (size_t)NNODES * CELLS;         // B*N*16

    dim3 grid(NNODES / 256), block(256);
    distana_step_kernel<<<grid, block, 0, stream>>>(
        input, w_pre, w_lstm, w_post, old_h, old_cell, y, new_h, new_cell);
}

// Round 2
// 42.379 us; speedup vs baseline: 1.0837x; 1.0837x over previous
//
#include <hip/hip_runtime.h>
#include <math.h>

// DISTANA fused prediction-kernel step.
// Shapes: B=128, N=4096, IN=9, PRE=4, CELLS=16, OUT=9.
// Outputs concatenated: y (B,N,9) | new_h (B,N,16) | new_cell (B,N,16), all f32.

#define NB 128
#define NN 4096
#define NNODES (NB * NN)   // 524288
#define IN_DIM 9
#define PRE_DIM 4
#define CELLS 16
#define OUT_DIM 9
#define NPB 256            // nodes per block (1 node per thread)

__device__ __forceinline__ float fast_rcp(float x) {
    return __builtin_amdgcn_rcpf(x);          // v_rcp_f32, ~1 ulp-ish approx
}

__device__ __forceinline__ float fast_tanh(float x) {
    // tanh(x) = (e^{2x}-1)/(e^{2x}+1); clamp so exp never overflows.
    x = fminf(fmaxf(x, -15.f), 15.f);
    float e = __expf(2.f * x);                // v_exp_f32 path
    return (e - 1.f) * fast_rcp(e + 1.f);
}

__global__ __launch_bounds__(256) void distana_step_kernel(
    const float* __restrict__ input,      // (B,N,9)
    const float* __restrict__ w_pre,      // (9,4)
    const float* __restrict__ w_lstm,     // (4,16)
    const float* __restrict__ w_post,     // (16,9)
    const float* __restrict__ old_h,      // (B,N,16)
    const float* __restrict__ old_cell,   // (B,N,16)
    float* __restrict__ y,                // (B,N,9)
    float* __restrict__ new_h,            // (B,N,16)
    float* __restrict__ new_cell)         // (B,N,16)
{
    __shared__ float sWpre[IN_DIM * PRE_DIM];    // 36
    __shared__ float sWl[PRE_DIM * CELLS];       // 64
    __shared__ float sWp[CELLS * OUT_DIM];       // 144
    __shared__ float sBuf[NPB * IN_DIM];         // 2304 floats; x then reused for y

    const int t = threadIdx.x;
    const int base = blockIdx.x * NPB;           // first node of this block
    const int idx = base + t;

    // ---- stage weights + input tile (fully coalesced float4) ----
    if (t < IN_DIM * PRE_DIM)  sWpre[t] = w_pre[t];
    if (t < PRE_DIM * CELLS)   sWl[t]   = w_lstm[t];
    if (t < CELLS * OUT_DIM)   sWp[t]   = w_post[t];

    // block's input tile: 256*9 floats = 576 float4, 16B-aligned (base*36B, base%256==0)
    const float4* gin4 = (const float4*)(input + (size_t)base * IN_DIM);
    float4* s4 = (float4*)sBuf;
    #pragma unroll
    for (int i = 0; i < 3; ++i) {
        int j = t + i * 256;
        if (j < (NPB * IN_DIM) / 4) s4[j] = gin4[j];
    }

    // ---- issue old_h / old_cell loads early (independent of LDS) ----
    const float4* hp = (const float4*)(old_h    + (size_t)idx * CELLS);
    const float4* cp = (const float4*)(old_cell + (size_t)idx * CELLS);
    float4 h4[4], c4[4];
    #pragma unroll
    for (int q = 0; q < 4; ++q) { h4[q] = hp[q]; c4[q] = cp[q]; }

    __syncthreads();

    // ---- pre = tanh(x @ W_pre)  (9->4); x from LDS (2-way bank alias = free) ----
    float x[IN_DIM];
    #pragma unroll
    for (int i = 0; i < IN_DIM; ++i) x[i] = sBuf[t * IN_DIM + i];

    float pre[PRE_DIM];
    #pragma unroll
    for (int p = 0; p < PRE_DIM; ++p) {
        float s = 0.f;
        #pragma unroll
        for (int i = 0; i < IN_DIM; ++i)
            s = fmaf(x[i], sWpre[i * PRE_DIM + p], s);
        pre[p] = fast_tanh(s);
    }

    __syncthreads();   // x region dead everywhere; sBuf can be reused for y

    // ---- CIFG cell: one exp + one rcp for BOTH gates per cell ----
    float oh[CELLS], oc[CELLS];
    #pragma unroll
    for (int q = 0; q < 4; ++q) {
        oh[q*4+0]=h4[q].x; oh[q*4+1]=h4[q].y; oh[q*4+2]=h4[q].z; oh[q*4+3]=h4[q].w;
        oc[q*4+0]=c4[q].x; oc[q*4+1]=c4[q].y; oc[q*4+2]=c4[q].z; oc[q*4+3]=c4[q].w;
    }

    float nh[CELLS], nc[CELLS];
    #pragma unroll
    for (int c = 0; c < CELLS; ++c) {
        float s = oh[c];
        #pragma unroll
        for (int p = 0; p < PRE_DIM; ++p)
            s = fmaf(pre[p], sWl[p * CELLS + c], s);
        s = fminf(fmaxf(s, -15.f), 15.f);
        float e  = __expf(s);                 // e^net
        float e2 = e * e;                     // e^{2 net}
        float a  = 1.f + e;
        float b  = 1.f + e2;
        float r  = fast_rcp(a * b);           // one rcp for both gates
        float ig = e * b * r;                 // sigmoid(net)
        float g  = (e2 - 1.f) * a * r;        // tanh(net)
        float ncv = fmaf(ig, g - oc[c], oc[c]);  // (1-i)*oc + i*g
        nc[c] = ncv;
        nh[c] = fast_tanh(ncv);
    }

    // ---- store new_h / new_cell (coalesced float4) ----
    float4* nhp = (float4*)(new_h    + (size_t)idx * CELLS);
    float4* ncp = (float4*)(new_cell + (size_t)idx * CELLS);
    #pragma unroll
    for (int q = 0; q < 4; ++q) {
        nhp[q] = make_float4(nh[q*4+0], nh[q*4+1], nh[q*4+2], nh[q*4+3]);
        ncp[q] = make_float4(nc[q*4+0], nc[q*4+1], nc[q*4+2], nc[q*4+3]);
    }

    // ---- y = tanh(new_h @ W_post) into LDS, then coalesced float4 store ----
    #pragma unroll
    for (int o = 0; o < OUT_DIM; ++o) {
        float s = 0.f;
        #pragma unroll
        for (int c = 0; c < CELLS; ++c)
            s = fmaf(nh[c], sWp[c * OUT_DIM + o], s);
        sBuf[t * OUT_DIM + o] = fast_tanh(s);
    }

    __syncthreads();

    float4* gy4 = (float4*)(y + (size_t)base * OUT_DIM);
    #pragma unroll
    for (int i = 0; i < 3; ++i) {
        int j = t + i * 256;
        if (j < (NPB * OUT_DIM) / 4) gy4[j] = s4[j];
    }
}

extern "C" void kernel_launch(void* const* d_in, const int* in_sizes, int n_in,
                              void* d_out, int out_size, void* d_ws, size_t ws_size,
                              hipStream_t stream) {
    const float* input    = (const float*)d_in[0];  // (B,N,9,1)
    const float* w_pre    = (const float*)d_in[1];  // (9,4)
    const float* w_lstm   = (const float*)d_in[2];  // (4,16)
    const float* w_post   = (const float*)d_in[3];  // (16,9)
    const float* old_h    = (const float*)d_in[4];  // (B,N,16)
    const float* old_cell = (const float*)d_in[5];  // (B,N,16)

    float* out = (float*)d_out;
    float* y        = out;                                    // B*N*9
    float* new_h    = out + (size_t)NNODES * OUT_DIM;         // B*N*16
    float* new_cell = new_h + (size_t)NNODES * CELLS;         // B*N*16

    dim3 grid(NNODES / NPB), block(256);
    distana_step_kernel<<<grid, block, 0, stream>>>(
        input, w_pre, w_lstm, w_post, old_h, old_cell, y, new_h, new_cell);
}